// Round 1
// baseline (526.511 us; speedup 1.0000x reference)
//
#include <hip/hip_runtime.h>
#include <hip/hip_fp16.h>
#include <type_traits>
#include <cstdint>
#include <cstddef>

#define TT 512
#define DFEAT 64
#define NPAIR 60
#define BIGF 1e10f

struct h4 { __half x, y, z, w; };

__constant__ int d_WI[9] = {0,0,0,1,1,2,2,3,3};
__constant__ int d_WJ[9] = {1,2,3,2,3,1,3,1,2};

// ---------------- cost kernel: Dm[p][i][j] = ||A_i||^2 + ||B_j||^2 - 2 A_i.B_j ----
template <typename CT>
__global__ __launch_bounds__(256) void cost_kernel(const float* __restrict__ data,
                                                   CT* __restrict__ Dm) {
  const int p = blockIdx.z;
  const int w = p / 15, jb = p % 15 + 1;
  const float* __restrict__ A = data + (size_t)(w * 16) * (TT * DFEAT);
  const float* __restrict__ B = data + (size_t)(w * 16 + jb) * (TT * DFEAT);
  const int i0 = blockIdx.y * 64, j0 = blockIdx.x * 64;
  __shared__ float As[64][65];
  __shared__ float Bs[64][65];
  __shared__ float a2[64], b2[64];
  const int tid = threadIdx.x;
#pragma unroll
  for (int s = 0; s < 4; ++s) {
    const int f = tid + s * 256;
    const int r = f >> 4, c4 = (f & 15) << 2;
    float4 va = *(const float4*)(A + (size_t)(i0 + r) * DFEAT + c4);
    As[r][c4 + 0] = va.x; As[r][c4 + 1] = va.y; As[r][c4 + 2] = va.z; As[r][c4 + 3] = va.w;
    float4 vb = *(const float4*)(B + (size_t)(j0 + r) * DFEAT + c4);
    Bs[r][c4 + 0] = vb.x; Bs[r][c4 + 1] = vb.y; Bs[r][c4 + 2] = vb.z; Bs[r][c4 + 3] = vb.w;
  }
  __syncthreads();
  if (tid < 64) {
    float s = 0.f;
#pragma unroll 8
    for (int k = 0; k < 64; ++k) s += As[tid][k] * As[tid][k];
    a2[tid] = s;
  } else if (tid < 128) {
    const int t = tid - 64;
    float s = 0.f;
#pragma unroll 8
    for (int k = 0; k < 64; ++k) s += Bs[t][k] * Bs[t][k];
    b2[t] = s;
  }
  __syncthreads();
  const int ty = tid >> 4, tx = tid & 15;
  float acc[4][4] = {};
#pragma unroll 4
  for (int k = 0; k < 64; ++k) {
    float av[4], bv[4];
#pragma unroll
    for (int r = 0; r < 4; ++r) av[r] = As[ty * 4 + r][k];
#pragma unroll
    for (int c = 0; c < 4; ++c) bv[c] = Bs[tx * 4 + c][k];
#pragma unroll
    for (int r = 0; r < 4; ++r)
#pragma unroll
      for (int c = 0; c < 4; ++c) acc[r][c] += av[r] * bv[c];
  }
  CT* __restrict__ Dp = Dm + (size_t)p * (TT * TT);
#pragma unroll
  for (int r = 0; r < 4; ++r) {
    const int gi = i0 + ty * 4 + r;
    const float ar = a2[ty * 4 + r];
    float o[4];
#pragma unroll
    for (int c = 0; c < 4; ++c) o[c] = ar + b2[tx * 4 + c] - 2.f * acc[r][c];
    if constexpr (std::is_same<CT, float>::value) {
      float4 v; v.x = o[0]; v.y = o[1]; v.z = o[2]; v.w = o[3];
      *(float4*)(Dp + (size_t)gi * TT + j0 + tx * 4) = v;
    } else {
      h4 v; v.x = __float2half(o[0]); v.y = __float2half(o[1]);
      v.z = __float2half(o[2]); v.w = __float2half(o[3]);
      *(h4*)(Dp + (size_t)gi * TT + j0 + tx * 4) = v;
    }
  }
}

// ---------------- soft-DTW DP: anti-diagonal wavefront, one thread per row ------
template <typename CT>
__global__ __launch_bounds__(512) void dp_kernel(const CT* __restrict__ Dm,
                                                 const int* __restrict__ lens,
                                                 float* __restrict__ raw) {
  const int p = blockIdx.x;
  const int w = p / 15, jb = p % 15 + 1;
  const int la = lens[w * 16];
  const int lb = lens[w * 16 + jb];
  const int kmax = la + lb;
  const int tid = threadIdx.x;
  const int i = tid + 1;  // row 1..512
  const CT* __restrict__ crow = Dm + (size_t)p * (TT * TT) + (size_t)(i - 1) * TT;
  __shared__ float buf[3][TT + 2];
  buf[0][i] = BIGF;
  buf[1][i] = BIGF;
  if (tid == 0) { buf[0][0] = 0.f; buf[1][0] = BIGF; }
  __syncthreads();
  float cprev = BIGF;  // R[i, k-1-i] (own cell of previous diagonal)
  float costv = (float)crow[min(max(1 - i, 0), TT - 1)];  // cost for k=2
  int ib2 = 0, ib1 = 1, ibw = 2;
  for (int k = 2; k <= kmax; ++k) {
    // prefetch next step's cost (address independent of DP values)
    const int jn = k + 1 - i;
    const float costn = (float)crow[min(max(jn - 1, 0), TT - 1)];
    const float a = buf[ib2][i - 1];   // R[i-1, j-1]
    const float b = buf[ib1][i - 1];   // R[i-1, j]
    const float m = fminf(fminf(a, b), cprev);
    const float s = __expf((m - a) * 0.2f) + __expf((m - b) * 0.2f) +
                    __expf((m - cprev) * 0.2f);
    const float smin = m - 5.0f * __logf(s);
    const int jc = k - i;
    const float cur = (jc >= 1 && jc <= TT) ? (costv + smin) : BIGF;
    buf[ibw][i] = cur;
    if (tid == 0) buf[ibw][0] = BIGF;  // i=0 boundary stays BIG for k>=1
    __syncthreads();
    cprev = cur;
    costv = costn;
    const int t = ib2; ib2 = ib1; ib1 = ibw; ibw = t;
  }
  if (i == la) raw[p] = cprev;  // R[la, lb]
}

// ---------------- Gram partials: 44 vectors (dim 32768), K-chunked -------------
__global__ __launch_bounds__(256) void gram_kernel(const float* __restrict__ data,
                                                   float* __restrict__ partials) {
  const int c = blockIdx.x;  // chunk of 512 floats, 64 chunks
  __shared__ float X[44][516];
  const int tid = threadIdx.x;
#pragma unroll
  for (int s = 0; s < 22; ++s) {
    const int f = tid + s * 256;          // 0..5631 float4s
    const int r = f >> 7;                 // row 0..43
    const int c4 = (f & 127) << 2;
    const int n = (r / 11) * 16 + (r % 11);
    float4 v = *(const float4*)(data + (size_t)n * (TT * DFEAT) + c * 512 + c4);
    X[r][c4 + 0] = v.x; X[r][c4 + 1] = v.y; X[r][c4 + 2] = v.z; X[r][c4 + 3] = v.w;
  }
  __syncthreads();
  for (int e = tid; e < 44 * 44; e += 256) {
    const int ii = e / 44, jj = e % 44;
    const float* xi = &X[ii][0];
    const float* xj = &X[jj][0];
    float acc = 0.f;
#pragma unroll 8
    for (int k = 0; k < 512; k += 4) {
      float4 u = *(const float4*)(xi + k);
      float4 v = *(const float4*)(xj + k);
      acc += u.x * v.x + u.y * v.y + u.z * v.z + u.w * v.w;
    }
    partials[(size_t)c * (44 * 44) + e] = acc;
  }
}

// ---------------- final: reduce Gram, triplet loss, MMD assembly ---------------
__device__ __forceinline__ float blockReduceSum(float v, float* sred) {
#pragma unroll
  for (int off = 32; off > 0; off >>= 1) v += __shfl_down(v, off);
  const int tid = threadIdx.x;
  if ((tid & 63) == 0) sred[tid >> 6] = v;
  __syncthreads();
  const float r = sred[0] + sred[1] + sred[2] + sred[3];
  __syncthreads();
  return r;
}

__global__ __launch_bounds__(256) void final_kernel(const float* __restrict__ partials,
                                                    const float* __restrict__ raw,
                                                    const int* __restrict__ lens,
                                                    float* __restrict__ out) {
  __shared__ float G[44 * 44];
  __shared__ float sred[4];
  const int tid = threadIdx.x;
  for (int e = tid; e < 44 * 44; e += 256) {
    float s = 0.f;
    for (int cc = 0; cc < 64; ++cc) s += partials[(size_t)cc * (44 * 44) + e];
    G[e] = s;
  }
  __syncthreads();
  float maxm = 0.f;  // meaningful on thread 0 (includes the zero-padding of mmds)
  for (int pp = 0; pp < 9; ++pp) {
    const int wi = d_WI[pp], wj = d_WJ[pp];
    // pass 1: sum of pairwise squared distances over 22x22
    float part = 0.f;
    for (int e = tid; e < 484; e += 256) {
      const int p = e / 22, q = e % 22;
      const int vp = (p < 11) ? (wi * 11 + p) : (wj * 11 + p - 11);
      const int vq = (q < 11) ? (wi * 11 + q) : (wj * 11 + q - 11);
      part += G[vp * 44 + vp] + G[vq * 44 + vq] - 2.f * G[vp * 44 + vq];
    }
    const float suml2 = blockReduceSum(part, sred);
    const float bw = suml2 / 462.0f * 0.25f;  // /(m^2-m) then /K_MUL^(K_NUM//2)
    // pass 2: multi-kernel sums per quadrant
    float aXX = 0.f, aXY = 0.f, aYX = 0.f, aYY = 0.f;
    for (int e = tid; e < 484; e += 256) {
      const int p = e / 22, q = e % 22;
      const int vp = (p < 11) ? (wi * 11 + p) : (wj * 11 + p - 11);
      const int vq = (q < 11) ? (wi * 11 + q) : (wj * 11 + q - 11);
      const float l2 = G[vp * 44 + vp] + G[vq * 44 + vq] - 2.f * G[vp * 44 + vq];
      float kk = 0.f;
      float inv = 1.0f / bw;
#pragma unroll
      for (int t = 0; t < 5; ++t) { kk += __expf(-l2 * inv); inv *= 0.5f; }
      const bool pl = p < 11, ql = q < 11;
      aXX += (pl && ql) ? kk : 0.f;
      aXY += (pl && !ql) ? kk : 0.f;
      aYX += (!pl && ql) ? kk : 0.f;
      aYY += (!pl && !ql) ? kk : 0.f;
    }
    const float sXX = blockReduceSum(aXX, sred);
    const float sXY = blockReduceSum(aXY, sred);
    const float sYX = blockReduceSum(aYX, sred);
    const float sYY = blockReduceSum(aYY, sred);
    if (tid == 0) {
      const float mmd = (sXX + sYY - sXY - sYX) / 121.f;
      maxm = fmaxf(maxm, mmd);
    }
  }
  if (tid == 0) {
    float total = 0.f;
    for (int w = 0; w < 4; ++w) {
      const int la0 = lens[w * 16];
      float dist[15];
      for (int q = 0; q < 15; ++q) {
        const int lb = lens[w * 16 + q + 1];
        dist[q] = raw[w * 15 + q] / (float)(la0 + lb);
      }
      const float mg = (dist[0] + dist[1] + dist[2] + dist[3] + dist[4]) * 0.2f;
      const float dk = sqrtf(fabsf(mg));
      float dg[5], dn[10];
      for (int q = 0; q < 5; ++q) dg[q] = dist[q] / dk;
      for (int q = 0; q < 10; ++q) dn[q] = dist[5 + q] / dk;
      float lsum = 0.f, cnt = 0.f;
      for (int a = 0; a < 5; ++a)
        for (int b = 0; b < 10; ++b) {
          const float v = dg[a] + 1.0f - dn[b];
          if (v > 0.f) { lsum += v; cnt += 1.f; }
        }
      const float ca = (dg[0] + dg[1] + dg[2] + dg[3] + dg[4]) * 0.2f;
      const float cb = (dn[0] + dn[1] + dn[2] + dn[3] + dn[4]) * 0.2f;
      float intra = 0.f;
      for (int q = 0; q < 5; ++q) intra += dg[q] - ca;
      const float inter = fmaxf(1.0f - fabsf(ca - cb), 0.f);
      total += lsum / (cnt + 1.0f) + 0.1f * intra + 0.1f * inter;
    }
    total *= 0.25f;
    out[0] = total + 0.1f * maxm;
  }
}

// ---------------- launch ---------------------------------------------------------
extern "C" void kernel_launch(void* const* d_in, const int* in_sizes, int n_in,
                              void* d_out, int out_size, void* d_ws, size_t ws_size,
                              hipStream_t stream) {
  const float* data = (const float*)d_in[0];
  const int* lens = (const int*)d_in[1];
  float* out = (float*)d_out;
  char* ws = (char*)d_ws;

  const size_t DMF = (size_t)NPAIR * TT * TT * sizeof(float);   // 62.9 MB
  const size_t DMH = (size_t)NPAIR * TT * TT * sizeof(__half);  // 31.5 MB
  const size_t RAWB = 1024;                                     // 60 floats, padded
  const size_t PARTB = (size_t)64 * 44 * 44 * sizeof(float);    // 495 KB

  if (ws_size >= DMF + RAWB + PARTB) {
    float* Dm = (float*)ws;
    float* raw = (float*)(ws + DMF);
    float* partials = (float*)(ws + DMF + RAWB);
    cost_kernel<float><<<dim3(8, 8, NPAIR), 256, 0, stream>>>(data, Dm);
    dp_kernel<float><<<NPAIR, 512, 0, stream>>>(Dm, lens, raw);
    gram_kernel<<<64, 256, 0, stream>>>(data, partials);
    final_kernel<<<1, 256, 0, stream>>>(partials, raw, lens, out);
  } else {
    __half* Dm = (__half*)ws;
    float* raw = (float*)(ws + DMH);
    float* partials = (float*)(ws + DMH + RAWB);
    cost_kernel<__half><<<dim3(8, 8, NPAIR), 256, 0, stream>>>(data, Dm);
    dp_kernel<__half><<<NPAIR, 512, 0, stream>>>(Dm, lens, raw);
    gram_kernel<<<64, 256, 0, stream>>>(data, partials);
    final_kernel<<<1, 256, 0, stream>>>(partials, raw, lens, out);
  }
}

// Round 2
// 360.439 us; speedup vs baseline: 1.4607x; 1.4607x over previous
//
#include <hip/hip_runtime.h>
#include <hip/hip_fp16.h>
#include <type_traits>
#include <cstdint>
#include <cstddef>

#define TT 512
#define DFEAT 64
#define NPAIR 60
#define BIGF 1e10f
// transformed domain: X = -R / (gamma*ln2), gamma = 5
#define INV_GLN2 0.28853900817779268f   // 1/(5*ln2)
#define NEG_GLN2 -3.4657359027997265f   // -(5*ln2)
#define XBIG (-2.8853900817779268e9f)   // -BIG/(5*ln2)

struct h4 { __half x, y, z, w; };

__constant__ int d_WI[9] = {0,0,0,1,1,2,2,3,3};
__constant__ int d_WJ[9] = {1,2,3,2,3,1,3,1,2};

#if __has_builtin(__builtin_amdgcn_exp2f)
__device__ __forceinline__ float fexp2(float x) { return __builtin_amdgcn_exp2f(x); }
#else
__device__ __forceinline__ float fexp2(float x) { return __expf(0.6931471805599453f * x); }
#endif
#if __has_builtin(__builtin_amdgcn_logf)
__device__ __forceinline__ float flog2(float x) { return __builtin_amdgcn_logf(x); }
#else
__device__ __forceinline__ float flog2(float x) { return 1.4426950408889634f * __logf(x); }
#endif

// ---- cost kernel: writes band-transposed, pre-scaled cost ----------------------
// layout: Dm[p][band(64)][col(512)][row_in_band(8)],  value = -cost * INV_GLN2
template <typename CT>
__global__ __launch_bounds__(256) void cost_kernel(const float* __restrict__ data,
                                                   CT* __restrict__ Dm) {
  const int p = blockIdx.z;
  const int w = p / 15, jb = p % 15 + 1;
  const float* __restrict__ A = data + (size_t)(w * 16) * (TT * DFEAT);
  const float* __restrict__ B = data + (size_t)(w * 16 + jb) * (TT * DFEAT);
  const int i0 = blockIdx.y * 64, j0 = blockIdx.x * 64;
  __shared__ float As[64][65];
  __shared__ float Bs[64][65];
  __shared__ float a2[64], b2[64];
  const int tid = threadIdx.x;
#pragma unroll
  for (int s = 0; s < 4; ++s) {
    const int f = tid + s * 256;
    const int r = f >> 4, c4 = (f & 15) << 2;
    float4 va = *(const float4*)(A + (size_t)(i0 + r) * DFEAT + c4);
    As[r][c4 + 0] = va.x; As[r][c4 + 1] = va.y; As[r][c4 + 2] = va.z; As[r][c4 + 3] = va.w;
    float4 vb = *(const float4*)(B + (size_t)(j0 + r) * DFEAT + c4);
    Bs[r][c4 + 0] = vb.x; Bs[r][c4 + 1] = vb.y; Bs[r][c4 + 2] = vb.z; Bs[r][c4 + 3] = vb.w;
  }
  __syncthreads();
  if (tid < 64) {
    float s = 0.f;
#pragma unroll 8
    for (int k = 0; k < 64; ++k) s += As[tid][k] * As[tid][k];
    a2[tid] = s;
  } else if (tid < 128) {
    const int t = tid - 64;
    float s = 0.f;
#pragma unroll 8
    for (int k = 0; k < 64; ++k) s += Bs[t][k] * Bs[t][k];
    b2[t] = s;
  }
  __syncthreads();
  const int ty = tid >> 4, tx = tid & 15;
  float acc[4][4] = {};
#pragma unroll 4
  for (int k = 0; k < 64; ++k) {
    float av[4], bv[4];
#pragma unroll
    for (int r = 0; r < 4; ++r) av[r] = As[ty * 4 + r][k];
#pragma unroll
    for (int c = 0; c < 4; ++c) bv[c] = Bs[tx * 4 + c][k];
#pragma unroll
    for (int r = 0; r < 4; ++r)
#pragma unroll
      for (int c = 0; c < 4; ++c) acc[r][c] += av[r] * bv[c];
  }
  CT* __restrict__ Dp = Dm + (size_t)p * (TT * TT);
  const int band = (i0 >> 3) + (ty >> 1);
  const int sub = (ty & 1) * 4;  // row-quad within the 8-row band
#pragma unroll
  for (int c = 0; c < 4; ++c) {
    const int gj = j0 + tx * 4 + c;
    float o[4];
#pragma unroll
    for (int r = 0; r < 4; ++r)
      o[r] = -(a2[ty * 4 + r] + b2[tx * 4 + c] - 2.f * acc[r][c]) * INV_GLN2;
    if constexpr (std::is_same<CT, float>::value) {
      float4 v; v.x = o[0]; v.y = o[1]; v.z = o[2]; v.w = o[3];
      *(float4*)(Dp + (size_t)band * (TT * 8) + (size_t)gj * 8 + sub) = v;
    } else {
      h4 v; v.x = __float2half(o[0]); v.y = __float2half(o[1]);
      v.z = __float2half(o[2]); v.w = __float2half(o[3]);
      *(h4*)(Dp + (size_t)band * (TT * 8) + (size_t)gj * 8 + sub) = v;
    }
  }
}

// ---- cost fetch helpers --------------------------------------------------------
__device__ __forceinline__ void load8(const float* __restrict__ base, int cc, float* o) {
  const float4* b4 = (const float4*)(base + (size_t)cc * 8);
  float4 a = b4[0], b = b4[1];
  o[0] = a.x; o[1] = a.y; o[2] = a.z; o[3] = a.w;
  o[4] = b.x; o[5] = b.y; o[6] = b.z; o[7] = b.w;
}
__device__ __forceinline__ void load8(const __half* __restrict__ base, int cc, float* o) {
  float4 v = *(const float4*)(base + (size_t)cc * 8);
  const __half2* h = (const __half2*)&v;
#pragma unroll
  for (int q = 0; q < 4; ++q) {
    o[2 * q] = __low2float(h[q]);
    o[2 * q + 1] = __high2float(h[q]);
  }
}

// ---- soft-DTW DP: one wave per pair, 8 rows per lane, shuffle pipeline ---------
template <typename CT>
__global__ __launch_bounds__(64) void dp_kernel(const CT* __restrict__ Dm,
                                                const int* __restrict__ lens,
                                                float* __restrict__ raw) {
  const int p = blockIdx.x;
  const int w = p / 15, jb = p % 15 + 1;
  const int la = lens[w * 16];
  const int lb = lens[w * 16 + jb];
  const int t = threadIdx.x;            // lane 0..63, owns rows 8t+1 .. 8t+8
  const int L = (la - 1) >> 3;          // lane holding row la
  const int dsel = (la - 1) & 7;
  const int s_end = lb + L;

  const CT* __restrict__ base = Dm + (size_t)p * (TT * TT) + (size_t)t * (TT * 8);

  float Xp[8];                          // X[row r0+d][current column - 1]
#pragma unroll
  for (int d = 0; d < 8; ++d) Xp[d] = XBIG;   // column-0 boundary
  float upA = (t == 0) ? 0.f : XBIG;    // X[r0-1][c-1] for next step
  float upB = XBIG;                     // X[r0-1][c]   for next step

  float cc_cur[8], cc_n1[8];
  load8(base, 0, cc_cur);                         // column c(s=1)
  load8(base, (t == 0) ? 1 : 0, cc_n1);           // column c+1

  for (int s = 1; s <= s_end; ++s) {
    const int cpf = min(max(s - t + 1, 0), TT - 1);  // prefetch col index (0-based)
    float n2[8];
    load8(base, cpf, n2);
    const int c = s - t;
    if (c >= 1 && c <= TT) {
      float carryA = upA;   // A for d=0
      float Bv = upB;       // B for d=0
#pragma unroll
      for (int d = 0; d < 8; ++d) {
        const float A = carryA, B = Bv, C = Xp[d];
        const float M = fmaxf(fmaxf(A, B), C);
        const float e = fexp2(A - M) + fexp2(B - M) + fexp2(C - M);
        const float X = cc_cur[d] + M + flog2(e);
        carryA = C;        // old Xp[d] is A for cell d+1
        Bv = X;
        Xp[d] = X;
      }
    }
    const float sh = __shfl_up(Xp[7], 1);
    upA = upB;
    upB = (t == 0) ? XBIG : sh;
#pragma unroll
    for (int d = 0; d < 8; ++d) { cc_cur[d] = cc_n1[d]; cc_n1[d] = n2[d]; }
  }
  if (t == L) {
    float xv = Xp[0];
#pragma unroll
    for (int d = 1; d < 8; ++d)
      if (dsel == d) xv = Xp[d];
    raw[p] = NEG_GLN2 * xv;   // back to R domain
  }
}

// ---- Gram partials: 44 vectors (dim 32768), K-chunked --------------------------
__global__ __launch_bounds__(256) void gram_kernel(const float* __restrict__ data,
                                                   float* __restrict__ partials) {
  const int c = blockIdx.x;  // chunk of 512 floats, 64 chunks
  __shared__ float X[44][516];
  const int tid = threadIdx.x;
#pragma unroll
  for (int s = 0; s < 22; ++s) {
    const int f = tid + s * 256;
    const int r = f >> 7;
    const int c4 = (f & 127) << 2;
    const int n = (r / 11) * 16 + (r % 11);
    float4 v = *(const float4*)(data + (size_t)n * (TT * DFEAT) + c * 512 + c4);
    X[r][c4 + 0] = v.x; X[r][c4 + 1] = v.y; X[r][c4 + 2] = v.z; X[r][c4 + 3] = v.w;
  }
  __syncthreads();
  for (int e = tid; e < 44 * 44; e += 256) {
    const int ii = e / 44, jj = e % 44;
    const float* xi = &X[ii][0];
    const float* xj = &X[jj][0];
    float acc = 0.f;
#pragma unroll 8
    for (int k = 0; k < 512; k += 4) {
      float4 u = *(const float4*)(xi + k);
      float4 v = *(const float4*)(xj + k);
      acc += u.x * v.x + u.y * v.y + u.z * v.z + u.w * v.w;
    }
    partials[(size_t)c * (44 * 44) + e] = acc;
  }
}

// ---- final: reduce Gram, triplet loss, MMD assembly ----------------------------
__device__ __forceinline__ float blockReduceSum(float v, float* sred) {
#pragma unroll
  for (int off = 32; off > 0; off >>= 1) v += __shfl_down(v, off);
  const int tid = threadIdx.x;
  if ((tid & 63) == 0) sred[tid >> 6] = v;
  __syncthreads();
  const float r = sred[0] + sred[1] + sred[2] + sred[3];
  __syncthreads();
  return r;
}

__global__ __launch_bounds__(256) void final_kernel(const float* __restrict__ partials,
                                                    const float* __restrict__ raw,
                                                    const int* __restrict__ lens,
                                                    float* __restrict__ out) {
  __shared__ float G[44 * 44];
  __shared__ float sred[4];
  const int tid = threadIdx.x;
  for (int e = tid; e < 44 * 44; e += 256) {
    float s = 0.f;
    for (int cc = 0; cc < 64; ++cc) s += partials[(size_t)cc * (44 * 44) + e];
    G[e] = s;
  }
  __syncthreads();
  float maxm = 0.f;
  for (int pp = 0; pp < 9; ++pp) {
    const int wi = d_WI[pp], wj = d_WJ[pp];
    float part = 0.f;
    for (int e = tid; e < 484; e += 256) {
      const int p = e / 22, q = e % 22;
      const int vp = (p < 11) ? (wi * 11 + p) : (wj * 11 + p - 11);
      const int vq = (q < 11) ? (wi * 11 + q) : (wj * 11 + q - 11);
      part += G[vp * 44 + vp] + G[vq * 44 + vq] - 2.f * G[vp * 44 + vq];
    }
    const float suml2 = blockReduceSum(part, sred);
    const float bw = suml2 / 462.0f * 0.25f;
    float aXX = 0.f, aXY = 0.f, aYX = 0.f, aYY = 0.f;
    for (int e = tid; e < 484; e += 256) {
      const int p = e / 22, q = e % 22;
      const int vp = (p < 11) ? (wi * 11 + p) : (wj * 11 + p - 11);
      const int vq = (q < 11) ? (wi * 11 + q) : (wj * 11 + q - 11);
      const float l2 = G[vp * 44 + vp] + G[vq * 44 + vq] - 2.f * G[vp * 44 + vq];
      float kk = 0.f;
      float inv = 1.0f / bw;
#pragma unroll
      for (int tkr = 0; tkr < 5; ++tkr) { kk += __expf(-l2 * inv); inv *= 0.5f; }
      const bool pl = p < 11, ql = q < 11;
      aXX += (pl && ql) ? kk : 0.f;
      aXY += (pl && !ql) ? kk : 0.f;
      aYX += (!pl && ql) ? kk : 0.f;
      aYY += (!pl && !ql) ? kk : 0.f;
    }
    const float sXX = blockReduceSum(aXX, sred);
    const float sXY = blockReduceSum(aXY, sred);
    const float sYX = blockReduceSum(aYX, sred);
    const float sYY = blockReduceSum(aYY, sred);
    if (tid == 0) {
      const float mmd = (sXX + sYY - sXY - sYX) / 121.f;
      maxm = fmaxf(maxm, mmd);
    }
  }
  if (tid == 0) {
    float total = 0.f;
    for (int w = 0; w < 4; ++w) {
      const int la0 = lens[w * 16];
      float dist[15];
      for (int q = 0; q < 15; ++q) {
        const int lb = lens[w * 16 + q + 1];
        dist[q] = raw[w * 15 + q] / (float)(la0 + lb);
      }
      const float mg = (dist[0] + dist[1] + dist[2] + dist[3] + dist[4]) * 0.2f;
      const float dk = sqrtf(fabsf(mg));
      float dg[5], dn[10];
      for (int q = 0; q < 5; ++q) dg[q] = dist[q] / dk;
      for (int q = 0; q < 10; ++q) dn[q] = dist[5 + q] / dk;
      float lsum = 0.f, cnt = 0.f;
      for (int a = 0; a < 5; ++a)
        for (int b = 0; b < 10; ++b) {
          const float v = dg[a] + 1.0f - dn[b];
          if (v > 0.f) { lsum += v; cnt += 1.f; }
        }
      const float ca = (dg[0] + dg[1] + dg[2] + dg[3] + dg[4]) * 0.2f;
      const float cb = (dn[0] + dn[1] + dn[2] + dn[3] + dn[4]) * 0.2f;
      float intra = 0.f;
      for (int q = 0; q < 5; ++q) intra += dg[q] - ca;
      const float inter = fmaxf(1.0f - fabsf(ca - cb), 0.f);
      total += lsum / (cnt + 1.0f) + 0.1f * intra + 0.1f * inter;
    }
    total *= 0.25f;
    out[0] = total + 0.1f * maxm;
  }
}

// ---- launch --------------------------------------------------------------------
extern "C" void kernel_launch(void* const* d_in, const int* in_sizes, int n_in,
                              void* d_out, int out_size, void* d_ws, size_t ws_size,
                              hipStream_t stream) {
  const float* data = (const float*)d_in[0];
  const int* lens = (const int*)d_in[1];
  float* out = (float*)d_out;
  char* ws = (char*)d_ws;

  const size_t DMF = (size_t)NPAIR * TT * TT * sizeof(float);   // 62.9 MB
  const size_t DMH = (size_t)NPAIR * TT * TT * sizeof(__half);  // 31.5 MB
  const size_t RAWB = 1024;
  const size_t PARTB = (size_t)64 * 44 * 44 * sizeof(float);

  if (ws_size >= DMF + RAWB + PARTB) {
    float* Dm = (float*)ws;
    float* raw = (float*)(ws + DMF);
    float* partials = (float*)(ws + DMF + RAWB);
    cost_kernel<float><<<dim3(8, 8, NPAIR), 256, 0, stream>>>(data, Dm);
    dp_kernel<float><<<NPAIR, 64, 0, stream>>>(Dm, lens, raw);
    gram_kernel<<<64, 256, 0, stream>>>(data, partials);
    final_kernel<<<1, 256, 0, stream>>>(partials, raw, lens, out);
  } else {
    __half* Dm = (__half*)ws;
    float* raw = (float*)(ws + DMH);
    float* partials = (float*)(ws + DMH + RAWB);
    cost_kernel<__half><<<dim3(8, 8, NPAIR), 256, 0, stream>>>(data, Dm);
    dp_kernel<__half><<<NPAIR, 64, 0, stream>>>(Dm, lens, raw);
    gram_kernel<<<64, 256, 0, stream>>>(data, partials);
    final_kernel<<<1, 256, 0, stream>>>(partials, raw, lens, out);
  }
}

// Round 4
// 317.366 us; speedup vs baseline: 1.6590x; 1.1357x over previous
//
#include <hip/hip_runtime.h>
#include <cstdint>
#include <cstddef>

#define TT 512
#define DFEAT 64
#define NPAIR 60
// transformed domain: E = exp(-R/gamma) = 2^(-R/(gamma*ln2)), gamma = 5
#define INV_GLN2 0.28853900817779268f   // 1/(5*ln2)
#define NEG_GLN2 -3.4657359027997265f   // -(5*ln2)
#define NEGE (-(1 << 29))               // exponent of E=0 boundary
#define BM 128
#define BK 64

__constant__ int d_WI[9] = {0,0,0,1,1,2,2,3,3};
__constant__ int d_WJ[9] = {1,2,3,2,3,1,3,1,2};

#if __has_builtin(__builtin_amdgcn_exp2f)
__device__ __forceinline__ float fexp2(float x) { return __builtin_amdgcn_exp2f(x); }
#else
__device__ __forceinline__ float fexp2(float x) { return __expf(0.6931471805599453f * x); }
#endif
#if __has_builtin(__builtin_amdgcn_logf)
__device__ __forceinline__ float flog2(float x) { return __builtin_amdgcn_logf(x); }
#else
__device__ __forceinline__ float flog2(float x) { return 1.4426950408889634f * __logf(x); }
#endif
#if __has_builtin(__builtin_amdgcn_ldexpf)
__device__ __forceinline__ float fldexp(float x, int n) { return __builtin_amdgcn_ldexpf(x, n); }
#else
__device__ __forceinline__ float fldexp(float x, int n) { return ldexpf(x, n); }
#endif
#if __has_builtin(__builtin_amdgcn_frexp_mantf)
__device__ __forceinline__ float fmant(float x) { return __builtin_amdgcn_frexp_mantf(x); }
#else
__device__ __forceinline__ float fmant(float x) { int e; return frexpf(x, &e); }
#endif
#if __has_builtin(__builtin_amdgcn_frexp_expf)
__device__ __forceinline__ int fexpo(float x) { return __builtin_amdgcn_frexp_expf(x); }
#else
__device__ __forceinline__ int fexpo(float x) { int e; frexpf(x, &e); return e; }
#endif

__device__ __forceinline__ unsigned short f2bf(float f) {
  unsigned u = __float_as_uint(f);
  unsigned r = (u + 0x7FFFu + ((u >> 16) & 1u)) >> 16;
  return (unsigned short)r;
}

// ---- norms: ||x||^2 per (seq, t) row ------------------------------------------
__global__ __launch_bounds__(256) void norms_kernel(const float* __restrict__ data,
                                                    float* __restrict__ norms) {
  const int g = blockIdx.x * 256 + threadIdx.x;  // 0..32767
  const float* __restrict__ row = data + (size_t)g * DFEAT;
  float s = 0.f;
#pragma unroll
  for (int k = 0; k < DFEAT; k += 4) {
    float4 v = *(const float4*)(row + k);
    s += v.x * v.x + v.y * v.y + v.z * v.z + v.w * v.w;
  }
  norms[g] = s;
}

// ---- cost kernel: w = 2^(-cost/(g*ln2)) as bf16, layout [p][band64][col512][8] --
__global__ __launch_bounds__(256) void cost_kernel(const float* __restrict__ data,
                                                   const float* __restrict__ norms,
                                                   const int* __restrict__ lens,
                                                   unsigned short* __restrict__ Dm) {
  const int p = blockIdx.z;
  const int w = p / 15, jb = p % 15 + 1;
  const int la = lens[w * 16], lb = lens[w * 16 + jb];
  const int i0 = blockIdx.y * BM, j0 = blockIdx.x * BM;
  if (i0 >= la || j0 >= lb) return;  // dead tiles never reach live DP cells
  const int an = w * 16, bn = w * 16 + jb;
  const float* __restrict__ A = data + (size_t)an * (TT * DFEAT);
  const float* __restrict__ B = data + (size_t)bn * (TT * DFEAT);

  __shared__ float smem[2 * BK * BM];  // As=[64][128], Bs=[64][128], 64KB
  float* As = smem;
  float* Bs = smem + BK * BM;

  const int tid = threadIdx.x;
  // staging: coalesced global float4 read, swizzled transpose write As[k][row^(k&24)]
#pragma unroll
  for (int s2 = 0; s2 < 8; ++s2) {
    const int f = tid + s2 * 256;   // 0..2047
    const int row = f >> 4;         // 0..127
    const int k4 = (f & 15) << 2;   // 0..60
    float4 va = *(const float4*)(A + (size_t)(i0 + row) * DFEAT + k4);
    float4 vb = *(const float4*)(B + (size_t)(j0 + row) * DFEAT + k4);
#pragma unroll
    for (int q = 0; q < 4; ++q) {
      const int k = k4 + q;
      const int cp = row ^ (k & 24);
      As[k * BM + cp] = ((const float*)&va)[q];
      Bs[k * BM + cp] = ((const float*)&vb)[q];
    }
  }
  const int ty = tid >> 4, tx = tid & 15;
  const int r0 = ty * 8, c0 = tx * 8;
  float aI[8], bI[8];
#pragma unroll
  for (int q = 0; q < 8; ++q) {
    aI[q] = norms[(size_t)an * TT + i0 + r0 + q] * INV_GLN2;
    bI[q] = norms[(size_t)bn * TT + j0 + c0 + q] * INV_GLN2;
  }
  __syncthreads();

  float acc[8][8] = {};
#pragma unroll 4
  for (int k = 0; k < BK; ++k) {
    const int v = k & 24;
    float af[8], bf8[8];
    *(float4*)&af[0] = *(const float4*)&As[k * BM + (r0 ^ v)];
    *(float4*)&af[4] = *(const float4*)&As[k * BM + (r0 ^ v) + 4];
    *(float4*)&bf8[0] = *(const float4*)&Bs[k * BM + (c0 ^ v)];
    *(float4*)&bf8[4] = *(const float4*)&Bs[k * BM + (c0 ^ v) + 4];
#pragma unroll
    for (int r = 0; r < 8; ++r)
#pragma unroll
      for (int cc = 0; cc < 8; ++cc)
        acc[r][cc] += af[r] * bf8[cc];
  }
  __syncthreads();  // done with As/Bs; reuse as bf16 stage [band16][col128][8]

  unsigned short* wst = (unsigned short*)smem;
  const float twoInv = 2.0f * INV_GLN2;
#pragma unroll
  for (int cc = 0; cc < 8; ++cc) {
    const int col = c0 + cc;
    unsigned short t8[8];
#pragma unroll
    for (int r = 0; r < 8; ++r) {
      const float x = twoInv * acc[r][cc] - aI[r] - bI[cc];
      t8[r] = f2bf(fexp2(x));  // w = 2^(-cost*INV_GLN2)
    }
    const int G = ty * 128 + col;          // thread's rows r0..r0+7 = band ty
    const int Gs = G ^ (tx & 7);           // bank swizzle (involution on low 3 bits)
    const unsigned u0 = (unsigned)t8[0] | ((unsigned)t8[1] << 16);
    const unsigned u1 = (unsigned)t8[2] | ((unsigned)t8[3] << 16);
    const unsigned u2 = (unsigned)t8[4] | ((unsigned)t8[5] << 16);
    const unsigned u3 = (unsigned)t8[6] | ((unsigned)t8[7] << 16);
    uint4 vv; vv.x = u0; vv.y = u1; vv.z = u2; vv.w = u3;
    *(uint4*)&wst[Gs * 8] = vv;
  }
  __syncthreads();
  // coalesced copy-out
  unsigned short* __restrict__ Dp = Dm + (size_t)p * (TT * TT);
#pragma unroll
  for (int s2 = 0; s2 < 8; ++s2) {
    const int g = tid + s2 * 256;  // granule (16B) index, 0..2047
    const int band = g >> 7, col = g & 127;
    const int Gs = g ^ ((col >> 3) & 7);
    uint4 vv = *(const uint4*)&wst[Gs * 8];
    *(uint4*)(Dp + (size_t)((i0 >> 3) + band) * (TT * 8) + (size_t)(j0 + col) * 8) = vv;
  }
}

// ---- soft-DTW DP in E-domain (mantissa, int exponent), 1 wave/pair -------------
__global__ __launch_bounds__(64) void dp_kernel(const unsigned short* __restrict__ Dm,
                                                const int* __restrict__ lens,
                                                float* __restrict__ raw) {
  const int p = blockIdx.x;
  const int w = p / 15, jb = p % 15 + 1;
  const int la = lens[w * 16];
  const int lb = lens[w * 16 + jb];
  const int t = threadIdx.x;           // lane, owns rows 8t+1..8t+8
  const int L = (la - 1) >> 3;
  const int dsel = (la - 1) & 7;
  const int s_end = lb + L;

  const unsigned short* __restrict__ base = Dm + (size_t)p * (TT * TT) + (size_t)t * (TT * 8);

  float Xm[8]; int Xe[8];
#pragma unroll
  for (int d = 0; d < 8; ++d) { Xm[d] = 0.f; Xe[d] = NEGE; }  // E=0 boundary
  float upAm = (t == 0) ? 0.5f : 0.f;  // E[r0-1][c-1]; lane0: E[0][0]=1=(0.5,1)
  int   upAe = (t == 0) ? 1 : NEGE;
  float upBm = 0.f;                    // E[r0-1][c] = 0
  int   upBe = NEGE;

  auto colidx = [&](int sigma) { return min(max(sigma - t - 1, 0), TT - 1); };
  auto ldcol = [&](int cc) { return *(const uint4*)(base + (size_t)cc * 8); };

  float WA[8], WB[8];
  uint4 q0 = ldcol(colidx(1));
  uint4 q1 = ldcol(colidx(2));
  uint4 RA = ldcol(colidx(3));
  uint4 RB = ldcol(colidx(4));
  {
    const unsigned ua[4] = {q0.x, q0.y, q0.z, q0.w};
    const unsigned ub[4] = {q1.x, q1.y, q1.z, q1.w};
#pragma unroll
    for (int i = 0; i < 4; ++i) {
      WA[2*i]   = __uint_as_float(ua[i] << 16);
      WA[2*i+1] = __uint_as_float(ua[i] & 0xFFFF0000u);
      WB[2*i]   = __uint_as_float(ub[i] << 16);
      WB[2*i+1] = __uint_as_float(ub[i] & 0xFFFF0000u);
    }
  }

  auto decode8 = [&](const uint4& q, float* o) {
    const unsigned u[4] = {q.x, q.y, q.z, q.w};
#pragma unroll
    for (int i = 0; i < 4; ++i) {
      o[2*i]   = __uint_as_float(u[i] << 16);
      o[2*i+1] = __uint_as_float(u[i] & 0xFFFF0000u);
    }
  };

  auto step = [&](int sigma, float* W) {
    const int c = sigma - t;
    if (c >= 1 && c <= TT) {
      float Am = upAm; int Ae = upAe;
      float Bm = upBm; int Be = upBe;
#pragma unroll
      for (int d = 0; d < 8; ++d) {
        const float Cm = Xm[d]; const int Ce = Xe[d];
        const int em = max(max(Ae, Be), Ce);
        const float sum = fldexp(Am, Ae - em) + fldexp(Cm, Ce - em) + fldexp(Bm, Be - em);
        const float pr = W[d] * sum;
        const float nm = fmant(pr);
        const int ne = em + fexpo(pr);
        Am = Cm; Ae = Ce;      // old X[d] is A for cell d+1
        Bm = nm; Be = ne;
        Xm[d] = nm; Xe[d] = ne;
      }
    }
    const float shm = __shfl_up(Xm[7], 1);
    const int she = __shfl_up(Xe[7], 1);
    upAm = upBm; upAe = upBe;
    upBm = (t == 0) ? 0.f : shm;
    upBe = (t == 0) ? NEGE : she;
  };

  int s = 1;
  for (; s + 1 <= s_end; s += 2) {
    step(s, WA);
    decode8(RA, WA);            // RA issued 2 steps ago
    RA = ldcol(colidx(s + 4));  // in flight for 2 steps, no rotation copies
    step(s + 1, WB);
    decode8(RB, WB);
    RB = ldcol(colidx(s + 5));
  }
  if (s <= s_end) step(s, WA);

  if (t == L) {
    float xm = Xm[0]; int xe = Xe[0];
#pragma unroll
    for (int d = 1; d < 8; ++d)
      if (dsel == d) { xm = Xm[d]; xe = Xe[d]; }
    raw[p] = NEG_GLN2 * ((float)xe + flog2(xm));  // R = -(g*ln2)*log2(E)
  }
}

// ---- Gram partials: 44 vectors (dim 32768), K-chunked --------------------------
__global__ __launch_bounds__(256) void gram_kernel(const float* __restrict__ data,
                                                   float* __restrict__ partials) {
  const int c = blockIdx.x;  // chunk of 512 floats, 64 chunks
  __shared__ float X[44][516];
  const int tid = threadIdx.x;
#pragma unroll
  for (int s = 0; s < 22; ++s) {
    const int f = tid + s * 256;
    const int r = f >> 7;
    const int c4 = (f & 127) << 2;
    const int n = (r / 11) * 16 + (r % 11);
    float4 v = *(const float4*)(data + (size_t)n * (TT * DFEAT) + c * 512 + c4);
    X[r][c4 + 0] = v.x; X[r][c4 + 1] = v.y; X[r][c4 + 2] = v.z; X[r][c4 + 3] = v.w;
  }
  __syncthreads();
  for (int e = tid; e < 44 * 44; e += 256) {
    const int ii = e / 44, jj = e % 44;
    const float* xi = &X[ii][0];
    const float* xj = &X[jj][0];
    float acc = 0.f;
#pragma unroll 8
    for (int k = 0; k < 512; k += 4) {
      float4 u = *(const float4*)(xi + k);
      float4 v = *(const float4*)(xj + k);
      acc += u.x * v.x + u.y * v.y + u.z * v.z + u.w * v.w;
    }
    partials[(size_t)c * (44 * 44) + e] = acc;
  }
}

// ---- final: reduce Gram, triplet loss, MMD assembly ----------------------------
__device__ __forceinline__ float blockReduceSum(float v, float* sred) {
#pragma unroll
  for (int off = 32; off > 0; off >>= 1) v += __shfl_down(v, off);
  const int tid = threadIdx.x;
  if ((tid & 63) == 0) sred[tid >> 6] = v;
  __syncthreads();
  const float r = sred[0] + sred[1] + sred[2] + sred[3];
  __syncthreads();
  return r;
}

__global__ __launch_bounds__(256) void final_kernel(const float* __restrict__ partials,
                                                    const float* __restrict__ raw,
                                                    const int* __restrict__ lens,
                                                    float* __restrict__ out) {
  __shared__ float G[44 * 44];
  __shared__ float sred[4];
  const int tid = threadIdx.x;
  for (int e = tid; e < 44 * 44; e += 256) {
    float s = 0.f;
    for (int cc = 0; cc < 64; ++cc) s += partials[(size_t)cc * (44 * 44) + e];
    G[e] = s;
  }
  __syncthreads();
  float maxm = 0.f;
  for (int pp = 0; pp < 9; ++pp) {
    const int wi = d_WI[pp], wj = d_WJ[pp];
    float part = 0.f;
    for (int e = tid; e < 484; e += 256) {
      const int p = e / 22, q = e % 22;
      const int vp = (p < 11) ? (wi * 11 + p) : (wj * 11 + p - 11);
      const int vq = (q < 11) ? (wi * 11 + q) : (wj * 11 + q - 11);
      part += G[vp * 44 + vp] + G[vq * 44 + vq] - 2.f * G[vp * 44 + vq];
    }
    const float suml2 = blockReduceSum(part, sred);
    const float bw = suml2 / 462.0f * 0.25f;
    float aXX = 0.f, aXY = 0.f, aYX = 0.f, aYY = 0.f;
    for (int e = tid; e < 484; e += 256) {
      const int p = e / 22, q = e % 22;
      const int vp = (p < 11) ? (wi * 11 + p) : (wj * 11 + p - 11);
      const int vq = (q < 11) ? (wi * 11 + q) : (wj * 11 + q - 11);
      const float l2 = G[vp * 44 + vp] + G[vq * 44 + vq] - 2.f * G[vp * 44 + vq];
      float kk = 0.f;
      float inv = 1.0f / bw;
#pragma unroll
      for (int tkr = 0; tkr < 5; ++tkr) { kk += __expf(-l2 * inv); inv *= 0.5f; }
      const bool pl = p < 11, ql = q < 11;
      aXX += (pl && ql) ? kk : 0.f;
      aXY += (pl && !ql) ? kk : 0.f;
      aYX += (!pl && ql) ? kk : 0.f;
      aYY += (!pl && !ql) ? kk : 0.f;
    }
    const float sXX = blockReduceSum(aXX, sred);
    const float sXY = blockReduceSum(aXY, sred);
    const float sYX = blockReduceSum(aYX, sred);
    const float sYY = blockReduceSum(aYY, sred);
    if (tid == 0) {
      const float mmd = (sXX + sYY - sXY - sYX) / 121.f;
      maxm = fmaxf(maxm, mmd);
    }
  }
  if (tid == 0) {
    float total = 0.f;
    for (int w = 0; w < 4; ++w) {
      const int la0 = lens[w * 16];
      float dist[15];
      for (int q = 0; q < 15; ++q) {
        const int lb = lens[w * 16 + q + 1];
        dist[q] = raw[w * 15 + q] / (float)(la0 + lb);
      }
      const float mg = (dist[0] + dist[1] + dist[2] + dist[3] + dist[4]) * 0.2f;
      const float dk = sqrtf(fabsf(mg));
      float dg[5], dn[10];
      for (int q = 0; q < 5; ++q) dg[q] = dist[q] / dk;
      for (int q = 0; q < 10; ++q) dn[q] = dist[5 + q] / dk;
      float lsum = 0.f, cnt = 0.f;
      for (int a = 0; a < 5; ++a)
        for (int b = 0; b < 10; ++b) {
          const float v = dg[a] + 1.0f - dn[b];
          if (v > 0.f) { lsum += v; cnt += 1.f; }
        }
      const float ca = (dg[0] + dg[1] + dg[2] + dg[3] + dg[4]) * 0.2f;
      const float cb = (dn[0] + dn[1] + dn[2] + dn[3] + dn[4]) * 0.2f;
      float intra = 0.f;
      for (int q = 0; q < 5; ++q) intra += dg[q] - ca;
      const float inter = fmaxf(1.0f - fabsf(ca - cb), 0.f);
      total += lsum / (cnt + 1.0f) + 0.1f * intra + 0.1f * inter;
    }
    total *= 0.25f;
    out[0] = total + 0.1f * maxm;
  }
}

// ---- launch --------------------------------------------------------------------
extern "C" void kernel_launch(void* const* d_in, const int* in_sizes, int n_in,
                              void* d_out, int out_size, void* d_ws, size_t ws_size,
                              hipStream_t stream) {
  const float* data = (const float*)d_in[0];
  const int* lens = (const int*)d_in[1];
  float* out = (float*)d_out;
  char* ws = (char*)d_ws;

  const size_t DMB = (size_t)NPAIR * TT * TT * sizeof(unsigned short);  // 31.46 MB
  const size_t RAWB = 1024;
  const size_t PARTB = (size_t)64 * 44 * 44 * sizeof(float);            // 495 KB

  unsigned short* Dm = (unsigned short*)ws;
  float* raw = (float*)(ws + DMB);
  float* partials = (float*)(ws + DMB + RAWB);
  float* norms = (float*)(ws + DMB + RAWB + PARTB);

  norms_kernel<<<128, 256, 0, stream>>>(data, norms);
  cost_kernel<<<dim3(4, 4, NPAIR), 256, 0, stream>>>(data, norms, lens, Dm);
  dp_kernel<<<NPAIR, 64, 0, stream>>>(Dm, lens, raw);
  gram_kernel<<<64, 256, 0, stream>>>(data, partials);
  final_kernel<<<1, 256, 0, stream>>>(partials, raw, lens, out);
}